// Round 1
// baseline (614.458 us; speedup 1.0000x reference)
//
#include <hip/hip_runtime.h>

// Problem: B=128, N=256, D=O=512.  R = B*N = 32768 rows.
// Pipeline: LN1 -> GEMM1(tanh) -> LN2 -> GEMM2(tanh)+residual -> LN3 -> GEMM3
//           -> masked softmax over the N axis.
// GEMMs use bf16 MFMA with hi/lo split (3 MFMA per tile) for ~fp32 accuracy.

#define RTOT 32768
#define DDIM 512
#define BB   128
#define NN   256

#define TM   128
#define TN   128
#define BKC  64
#define LDSS 72   // padded LDS row stride in ushorts (64 + 8 -> 2-way bank alias, free)

typedef __attribute__((ext_vector_type(8))) short bf16x8;
typedef __attribute__((ext_vector_type(4))) float f32x4;

__device__ __forceinline__ unsigned short f2bf(float f) {
  union { float f; unsigned u; } x; x.f = f;
  unsigned r = x.u + 0x7fffu + ((x.u >> 16) & 1u);   // round-to-nearest-even
  return (unsigned short)(r >> 16);
}
__device__ __forceinline__ float bf2f(unsigned short h) {
  union { unsigned u; float f; } x; x.u = ((unsigned)h) << 16;
  return x.f;
}
__device__ __forceinline__ float fast_tanh(float x) {
  // tanh(x) = 1 - 2/(e^{2x}+1); rcp err ~1e-7, safe for |x| < 40 (inf -> rcp=0 -> 1)
  float e = __expf(2.f * x);
  return 1.f - 2.f * __builtin_amdgcn_rcpf(e + 1.f);
}

// ---- Pre-split + transpose weights: W[d][o] fp32 -> WhiT/WloT[o][d] bf16 ----
__global__ void prep_w_kernel(const float* __restrict__ W1, const float* __restrict__ W2,
                              const float* __restrict__ W3,
                              unsigned short* __restrict__ WhiT, unsigned short* __restrict__ WloT) {
  int idx = blockIdx.x * 256 + threadIdx.x;   // 3 * 512 * 512 total
  int s   = idx >> 18;
  int rem = idx & 0x3FFFF;
  int o   = rem >> 9;
  int d   = rem & 511;
  const float* W = (s == 0) ? W1 : (s == 1) ? W2 : W3;
  float v = W[d * 512 + o];
  unsigned short hi = f2bf(v);
  unsigned short lo = f2bf(v - bf2f(hi));
  WhiT[idx] = hi;
  WloT[idx] = lo;
}

// ---- LayerNorm a 512-wide row, emit bf16 hi/lo planes ----
__global__ __launch_bounds__(256) void ln_kernel(const float* __restrict__ in,
                                                 const float* __restrict__ g,
                                                 const float* __restrict__ b,
                                                 unsigned short* __restrict__ outHi,
                                                 unsigned short* __restrict__ outLo) {
  int row = blockIdx.x;
  int t = threadIdx.x;                 // 256 threads, 2 elems each
  const float* x = in + ((size_t)row << 9);
  float2 v = *(const float2*)(x + t * 2);
  float s  = v.x + v.y;
  float sq = v.x * v.x + v.y * v.y;
  #pragma unroll
  for (int off = 32; off > 0; off >>= 1) {
    s  += __shfl_down(s, off, 64);
    sq += __shfl_down(sq, off, 64);
  }
  __shared__ float ws_s[4], ws_q[4];
  int wave = t >> 6, lane = t & 63;
  if (lane == 0) { ws_s[wave] = s; ws_q[wave] = sq; }
  __syncthreads();
  float tot  = ws_s[0] + ws_s[1] + ws_s[2] + ws_s[3];
  float totq = ws_q[0] + ws_q[1] + ws_q[2] + ws_q[3];
  float mean = tot * (1.f / 512.f);
  float var  = totq * (1.f / 512.f) - mean * mean;
  float inv  = 1.f / sqrtf(var + 1e-5f);
  float2 gg = *(const float2*)(g + t * 2);
  float2 bb = *(const float2*)(b + t * 2);
  float o0 = (v.x - mean) * inv * gg.x + bb.x;
  float o1 = (v.y - mean) * inv * gg.y + bb.y;
  unsigned short h0 = f2bf(o0), h1 = f2bf(o1);
  unsigned short l0 = f2bf(o0 - bf2f(h0)), l1 = f2bf(o1 - bf2f(h1));
  size_t base = ((size_t)row << 9) + t * 2;
  *(unsigned*)&outHi[base] = (unsigned)h0 | ((unsigned)h1 << 16);
  *(unsigned*)&outLo[base] = (unsigned)l0 | ((unsigned)l1 << 16);
}

// ---- Split-bf16 GEMM: C[R x 512] = A[R x 512] @ W[512 x 512], W given as W^T ----
// stage 0: F = tanh(acc)        (h1)
// stage 1: F = tanh(acc) + F    (r = h2 + h1, in place over h1)
// stage 2: F = acc              (o3)
__global__ __launch_bounds__(256, 2) void gemm_kernel(
    const unsigned short* __restrict__ Ahi, const unsigned short* __restrict__ Alo,
    const unsigned short* __restrict__ BhiT, const unsigned short* __restrict__ BloT,
    float* __restrict__ F, int stage) {
  __shared__ __align__(16) unsigned short sAhi[TM * LDSS];
  __shared__ __align__(16) unsigned short sAlo[TM * LDSS];
  __shared__ __align__(16) unsigned short sBhi[TN * LDSS];
  __shared__ __align__(16) unsigned short sBlo[TN * LDSS];

  int bx     = blockIdx.x;
  int rBase  = (bx >> 2) * TM;
  int nBase  = (bx & 3) * TN;

  int t     = threadIdx.x;
  int lane  = t & 63, wave = t >> 6;
  int wm    = wave & 1, wn = wave >> 1;
  int row16 = lane & 15, quad = lane >> 4;

  f32x4 acc[4][4] = {};

  int sr = t >> 3;          // staging row within pass (0..31)
  int sc = (t & 7) * 8;     // staging col (0..56)

  for (int k0 = 0; k0 < 512; k0 += BKC) {
    #pragma unroll
    for (int p = 0; p < 4; ++p) {
      int r = p * 32 + sr;
      size_t ga = (((size_t)(rBase + r)) << 9) + k0 + sc;
      size_t gb = (((size_t)(nBase + r)) << 9) + k0 + sc;
      *(uint4*)&sAhi[r * LDSS + sc] = *(const uint4*)(Ahi + ga);
      *(uint4*)&sAlo[r * LDSS + sc] = *(const uint4*)(Alo + ga);
      *(uint4*)&sBhi[r * LDSS + sc] = *(const uint4*)(BhiT + gb);
      *(uint4*)&sBlo[r * LDSS + sc] = *(const uint4*)(BloT + gb);
    }
    __syncthreads();

    #pragma unroll
    for (int kk = 0; kk < BKC; kk += 32) {
      bf16x8 ah[4], al[4], bh[4], bl[4];
      #pragma unroll
      for (int i = 0; i < 4; ++i) {
        int ao = (wm * 64 + i * 16 + row16) * LDSS + kk + quad * 8;
        int bo = (wn * 64 + i * 16 + row16) * LDSS + kk + quad * 8;
        ah[i] = *(const bf16x8*)&sAhi[ao];
        al[i] = *(const bf16x8*)&sAlo[ao];
        bh[i] = *(const bf16x8*)&sBhi[bo];
        bl[i] = *(const bf16x8*)&sBlo[bo];
      }
      #pragma unroll
      for (int mi = 0; mi < 4; ++mi)
        #pragma unroll
        for (int ni = 0; ni < 4; ++ni) {
          acc[mi][ni] = __builtin_amdgcn_mfma_f32_16x16x32_bf16(ah[mi], bh[ni], acc[mi][ni], 0, 0, 0);
          acc[mi][ni] = __builtin_amdgcn_mfma_f32_16x16x32_bf16(al[mi], bh[ni], acc[mi][ni], 0, 0, 0);
          acc[mi][ni] = __builtin_amdgcn_mfma_f32_16x16x32_bf16(ah[mi], bl[ni], acc[mi][ni], 0, 0, 0);
        }
    }
    __syncthreads();
  }

  #pragma unroll
  for (int mi = 0; mi < 4; ++mi) {
    #pragma unroll
    for (int ni = 0; ni < 4; ++ni) {
      int gc = nBase + wn * 64 + ni * 16 + row16;
      #pragma unroll
      for (int rg = 0; rg < 4; ++rg) {
        int gr = rBase + wm * 64 + mi * 16 + quad * 4 + rg;
        size_t idx = ((size_t)gr << 9) + gc;
        float v = acc[mi][ni][rg];
        if (stage == 0)      F[idx] = fast_tanh(v);
        else if (stage == 1) F[idx] = fast_tanh(v) + F[idx];
        else                 F[idx] = v;
      }
    }
  }
}

// ---- Masked softmax over the N axis (per batch b, per channel o) ----
__global__ __launch_bounds__(256) void softmax_kernel(const float* __restrict__ o3,
                                                      const int* __restrict__ mask,
                                                      float* __restrict__ out) {
  int b = blockIdx.y;
  int t = threadIdx.x;                  // 256
  int o = blockIdx.x * 256 + t;         // 0..511
  __shared__ int smask[NN];
  __shared__ int s_any;
  if (t == 0) s_any = 0;
  __syncthreads();
  int m = mask[b * NN + t];
  smask[t] = m;
  if (m) atomicOr(&s_any, 1);
  __syncthreads();
  if (t == 0 && !s_any) smask[0] = 1;   // _grant_at_least_one_valid
  __syncthreads();

  const float* base = o3 + (((size_t)b * NN) << 9) + o;
  float zmax = -3.4e38f;
  for (int n = 0; n < NN; ++n)
    if (smask[n]) zmax = fmaxf(zmax, base[(size_t)n << 9]);
  float sum = 0.f;
  for (int n = 0; n < NN; ++n)
    if (smask[n]) sum += __expf(base[(size_t)n << 9] - zmax);
  float invs = 1.f / sum;
  float* ob = out + (((size_t)b * NN) << 9) + o;
  for (int n = 0; n < NN; ++n) {
    float r = 0.f;
    if (smask[n]) r = __expf(base[(size_t)n << 9] - zmax) * invs;
    ob[(size_t)n << 9] = r;
  }
}

extern "C" void kernel_launch(void* const* d_in, const int* in_sizes, int n_in,
                              void* d_out, int out_size, void* d_ws, size_t ws_size,
                              hipStream_t stream) {
  const float* Obs = (const float*)d_in[0];
  const int*   msk = (const int*)d_in[1];
  const float* g1  = (const float*)d_in[2];
  const float* b1  = (const float*)d_in[3];
  const float* W1  = (const float*)d_in[4];
  const float* g2  = (const float*)d_in[5];
  const float* b2  = (const float*)d_in[6];
  const float* W2  = (const float*)d_in[7];
  const float* g3  = (const float*)d_in[8];
  const float* b3  = (const float*)d_in[9];
  const float* W3  = (const float*)d_in[10];
  float* out = (float*)d_out;

  char* ws = (char*)d_ws;
  const size_t PLANE_BF16 = (size_t)RTOT * DDIM * 2;   // 32 MB
  const size_t PLANE_F32  = (size_t)RTOT * DDIM * 4;   // 64 MB
  unsigned short* Ahi  = (unsigned short*)ws;
  unsigned short* Alo  = (unsigned short*)(ws + PLANE_BF16);
  float*          F1   = (float*)(ws + 2 * PLANE_BF16);
  unsigned short* WhiT = (unsigned short*)(ws + 2 * PLANE_BF16 + PLANE_F32);
  unsigned short* WloT = WhiT + 3 * 262144;

  prep_w_kernel<<<3072, 256, 0, stream>>>(W1, W2, W3, WhiT, WloT);

  ln_kernel<<<RTOT, 256, 0, stream>>>(Obs, g1, b1, Ahi, Alo);
  gemm_kernel<<<1024, 256, 0, stream>>>(Ahi, Alo, WhiT, WloT, F1, 0);

  ln_kernel<<<RTOT, 256, 0, stream>>>(F1, g2, b2, Ahi, Alo);
  gemm_kernel<<<1024, 256, 0, stream>>>(Ahi, Alo, WhiT + 262144, WloT + 262144, F1, 1);

  ln_kernel<<<RTOT, 256, 0, stream>>>(F1, g3, b3, Ahi, Alo);
  gemm_kernel<<<1024, 256, 0, stream>>>(Ahi, Alo, WhiT + 2 * 262144, WloT + 2 * 262144, F1, 2);

  softmax_kernel<<<dim3(2, BB), 256, 0, stream>>>(F1, msk, out);
}

// Round 2
// 465.632 us; speedup vs baseline: 1.3196x; 1.3196x over previous
//
#include <hip/hip_runtime.h>

// B=128, N=256, D=O=512. R = B*N = 32768 rows.
// LN1 -> GEMM1(tanh) -> LN2 -> GEMM2(tanh)+residual -> LN3 -> GEMM3 -> masked softmax over N.
// GEMMs: bf16 MFMA hi/lo split (3 MFMA/tile) for ~fp32 accuracy; global_load_lds staging.
// Softmax: LDS-staged single-read per (b, o-chunk) block.

#define RTOT 32768
#define DDIM 512
#define BB   128
#define NN   256

#define TM   128
#define TN   128
#define BKC  64
#define LDSS 64   // packed rows (128 B) — required by global_load_lds lane layout

typedef __attribute__((ext_vector_type(8))) short bf16x8;
typedef __attribute__((ext_vector_type(4))) float f32x4;

__device__ __forceinline__ unsigned short f2bf(float f) {
  union { float f; unsigned u; } x; x.f = f;
  unsigned r = x.u + 0x7fffu + ((x.u >> 16) & 1u);   // RNE
  return (unsigned short)(r >> 16);
}
__device__ __forceinline__ float bf2f(unsigned short h) {
  union { unsigned u; float f; } x; x.u = ((unsigned)h) << 16;
  return x.f;
}
__device__ __forceinline__ float fast_tanh(float x) {
  float e = __expf(2.f * x);
  return 1.f - 2.f * __builtin_amdgcn_rcpf(e + 1.f);
}
__device__ __forceinline__ void async_copy16(const unsigned short* g, unsigned short* l) {
  __builtin_amdgcn_global_load_lds(
      (const __attribute__((address_space(1))) unsigned int*)g,
      (__attribute__((address_space(3))) unsigned int*)l, 16, 0, 0);
}

// ---- Pre-split + transpose weights: W[d][o] fp32 -> WhiT/WloT[o][d] bf16 ----
__global__ void prep_w_kernel(const float* __restrict__ W1, const float* __restrict__ W2,
                              const float* __restrict__ W3,
                              unsigned short* __restrict__ WhiT, unsigned short* __restrict__ WloT) {
  int idx = blockIdx.x * 256 + threadIdx.x;   // 3 * 512 * 512 total
  int s   = idx >> 18;
  int rem = idx & 0x3FFFF;
  int o   = rem >> 9;
  int d   = rem & 511;
  const float* W = (s == 0) ? W1 : (s == 1) ? W2 : W3;
  float v = W[d * 512 + o];
  unsigned short hi = f2bf(v);
  unsigned short lo = f2bf(v - bf2f(hi));
  WhiT[idx] = hi;
  WloT[idx] = lo;
}

// ---- LayerNorm a 512-wide row, emit bf16 hi/lo planes ----
__global__ __launch_bounds__(256) void ln_kernel(const float* __restrict__ in,
                                                 const float* __restrict__ g,
                                                 const float* __restrict__ b,
                                                 unsigned short* __restrict__ outHi,
                                                 unsigned short* __restrict__ outLo) {
  int row = blockIdx.x;
  int t = threadIdx.x;                 // 256 threads, 2 elems each
  const float* x = in + ((size_t)row << 9);
  float2 v = *(const float2*)(x + t * 2);
  float s  = v.x + v.y;
  float sq = v.x * v.x + v.y * v.y;
  #pragma unroll
  for (int off = 32; off > 0; off >>= 1) {
    s  += __shfl_down(s, off, 64);
    sq += __shfl_down(sq, off, 64);
  }
  __shared__ float ws_s[4], ws_q[4];
  int wave = t >> 6, lane = t & 63;
  if (lane == 0) { ws_s[wave] = s; ws_q[wave] = sq; }
  __syncthreads();
  float tot  = ws_s[0] + ws_s[1] + ws_s[2] + ws_s[3];
  float totq = ws_q[0] + ws_q[1] + ws_q[2] + ws_q[3];
  float mean = tot * (1.f / 512.f);
  float var  = totq * (1.f / 512.f) - mean * mean;
  float inv  = 1.f / sqrtf(var + 1e-5f);
  float2 gg = *(const float2*)(g + t * 2);
  float2 bb = *(const float2*)(b + t * 2);
  float o0 = (v.x - mean) * inv * gg.x + bb.x;
  float o1 = (v.y - mean) * inv * gg.y + bb.y;
  unsigned short h0 = f2bf(o0), h1 = f2bf(o1);
  unsigned short l0 = f2bf(o0 - bf2f(h0)), l1 = f2bf(o1 - bf2f(h1));
  size_t base = ((size_t)row << 9) + t * 2;
  *(unsigned*)&outHi[base] = (unsigned)h0 | ((unsigned)h1 << 16);
  *(unsigned*)&outLo[base] = (unsigned)l0 | ((unsigned)l1 << 16);
}

// ---- Split-bf16 GEMM: C[R x 512] = A[R x 512] @ W[512 x 512], W given as W^T ----
// stage 0: F = tanh(acc); stage 1: F = tanh(acc) + F; stage 2: F = acc
__global__ __launch_bounds__(256, 2) void gemm_kernel(
    const unsigned short* __restrict__ Ahi, const unsigned short* __restrict__ Alo,
    const unsigned short* __restrict__ BhiT, const unsigned short* __restrict__ BloT,
    float* __restrict__ F, int stage) {
  __shared__ __align__(16) unsigned short sAhi[TM * LDSS];
  __shared__ __align__(16) unsigned short sAlo[TM * LDSS];
  __shared__ __align__(16) unsigned short sBhi[TN * LDSS];
  __shared__ __align__(16) unsigned short sBlo[TN * LDSS];

  int bx     = blockIdx.x;
  int rBase  = (bx >> 2) * TM;
  int nBase  = (bx & 3) * TN;

  int t     = threadIdx.x;
  int lane  = t & 63, wave = t >> 6;
  int wm    = wave & 1, wn = wave >> 1;
  int row16 = lane & 15, quad = lane >> 4;

  // DMA staging assignment: wave w stages plane w (8 rows per instr, 16 instrs)
  unsigned short* ldsPlane = (wave == 0) ? sAhi : (wave == 1) ? sAlo : (wave == 2) ? sBhi : sBlo;
  const unsigned short* gPlane = (wave == 0) ? Ahi : (wave == 1) ? Alo : (wave == 2) ? BhiT : BloT;
  int tileBase = (wave < 2) ? rBase : nBase;
  int lr = lane >> 3;          // row within 8-row group
  int lc = (lane & 7) * 8;     // ushort col within 64

  f32x4 acc[4][4] = {};

  for (int k0 = 0; k0 < 512; k0 += BKC) {
    #pragma unroll
    for (int p = 0; p < 16; ++p) {
      const unsigned short* g = gPlane + (((size_t)(tileBase + p * 8 + lr)) << 9) + k0 + lc;
      async_copy16(g, ldsPlane + p * 8 * LDSS);   // wave-uniform LDS base
    }
    __syncthreads();

    #pragma unroll
    for (int kk = 0; kk < BKC; kk += 32) {
      bf16x8 ah[4], al[4], bh[4], bl[4];
      #pragma unroll
      for (int i = 0; i < 4; ++i) {
        int ao = (wm * 64 + i * 16 + row16) * LDSS + kk + quad * 8;
        int bo = (wn * 64 + i * 16 + row16) * LDSS + kk + quad * 8;
        ah[i] = *(const bf16x8*)&sAhi[ao];
        al[i] = *(const bf16x8*)&sAlo[ao];
        bh[i] = *(const bf16x8*)&sBhi[bo];
        bl[i] = *(const bf16x8*)&sBlo[bo];
      }
      #pragma unroll
      for (int mi = 0; mi < 4; ++mi)
        #pragma unroll
        for (int ni = 0; ni < 4; ++ni) {
          acc[mi][ni] = __builtin_amdgcn_mfma_f32_16x16x32_bf16(ah[mi], bh[ni], acc[mi][ni], 0, 0, 0);
          acc[mi][ni] = __builtin_amdgcn_mfma_f32_16x16x32_bf16(al[mi], bh[ni], acc[mi][ni], 0, 0, 0);
          acc[mi][ni] = __builtin_amdgcn_mfma_f32_16x16x32_bf16(ah[mi], bl[ni], acc[mi][ni], 0, 0, 0);
        }
    }
    __syncthreads();
  }

  #pragma unroll
  for (int mi = 0; mi < 4; ++mi) {
    #pragma unroll
    for (int ni = 0; ni < 4; ++ni) {
      int gc = nBase + wn * 64 + ni * 16 + row16;
      #pragma unroll
      for (int rg = 0; rg < 4; ++rg) {
        int gr = rBase + wm * 64 + mi * 16 + quad * 4 + rg;
        size_t idx = ((size_t)gr << 9) + gc;
        float v = acc[mi][ni][rg];
        if (stage == 0)      F[idx] = fast_tanh(v);
        else if (stage == 1) F[idx] = fast_tanh(v) + F[idx];
        else                 F[idx] = v;
      }
    }
  }
}

// ---- Masked softmax over N: one block per (b, 64-o chunk), z staged in LDS ----
__global__ __launch_bounds__(256, 2) void softmax_kernel(const float* __restrict__ o3,
                                                         const int* __restrict__ mask,
                                                         float* __restrict__ out) {
  __shared__ float sz[NN * 64];        // [n][o_l] 64 KB
  __shared__ float sredm[4 * 64];
  __shared__ float sreds[4 * 64];
  __shared__ int   smask[NN];

  int b  = blockIdx.x >> 3;
  int oc = blockIdx.x & 7;
  int t  = threadIdx.x;
  int o_l = t & 63;                    // o within chunk
  int n_h = t >> 6;                    // 0..3

  int mt = mask[b * NN + t];
  int any = __syncthreads_or(mt);
  smask[t] = (t == 0 && !any) ? 1 : mt;   // _grant_at_least_one_valid
  __syncthreads();

  const float* src = o3 + (((size_t)(b * NN)) << 9) + oc * 64;
  // Load: thread covers n = j*4 + n_h, coalesced across o_l
  #pragma unroll 4
  for (int j = 0; j < 64; ++j) {
    int n = j * 4 + n_h;
    float v = src[((size_t)n << 9) + o_l];
    int m = smask[n];                  // wave-uniform broadcast
    sz[n * 64 + o_l] = m ? v : -3.4e38f;
  }
  __syncthreads();

  // Max over this thread's 64-n strip
  float mx = -3.4e38f;
  #pragma unroll 8
  for (int i = 0; i < 64; ++i)
    mx = fmaxf(mx, sz[(n_h * 64 + i) * 64 + o_l]);
  sredm[n_h * 64 + o_l] = mx;
  __syncthreads();
  float m4 = fmaxf(fmaxf(sredm[o_l], sredm[64 + o_l]),
                   fmaxf(sredm[128 + o_l], sredm[192 + o_l]));

  // Sum of exp
  float sm = 0.f;
  #pragma unroll 8
  for (int i = 0; i < 64; ++i)
    sm += __expf(sz[(n_h * 64 + i) * 64 + o_l] - m4);
  sreds[n_h * 64 + o_l] = sm;
  __syncthreads();
  float tot = sreds[o_l] + sreds[64 + o_l] + sreds[128 + o_l] + sreds[192 + o_l];
  float inv = 1.f / tot;

  float* dst = out + (((size_t)(b * NN)) << 9) + oc * 64;
  #pragma unroll 4
  for (int j = 0; j < 64; ++j) {
    int n = j * 4 + n_h;
    float z = sz[n * 64 + o_l];
    dst[((size_t)n << 9) + o_l] = __expf(z - m4) * inv;
  }
}

extern "C" void kernel_launch(void* const* d_in, const int* in_sizes, int n_in,
                              void* d_out, int out_size, void* d_ws, size_t ws_size,
                              hipStream_t stream) {
  const float* Obs = (const float*)d_in[0];
  const int*   msk = (const int*)d_in[1];
  const float* g1  = (const float*)d_in[2];
  const float* b1  = (const float*)d_in[3];
  const float* W1  = (const float*)d_in[4];
  const float* g2  = (const float*)d_in[5];
  const float* b2  = (const float*)d_in[6];
  const float* W2  = (const float*)d_in[7];
  const float* g3  = (const float*)d_in[8];
  const float* b3  = (const float*)d_in[9];
  const float* W3  = (const float*)d_in[10];
  float* out = (float*)d_out;

  char* ws = (char*)d_ws;
  const size_t PLANE_BF16 = (size_t)RTOT * DDIM * 2;   // 32 MB
  const size_t PLANE_F32  = (size_t)RTOT * DDIM * 4;   // 64 MB
  unsigned short* Ahi  = (unsigned short*)ws;
  unsigned short* Alo  = (unsigned short*)(ws + PLANE_BF16);
  float*          F1   = (float*)(ws + 2 * PLANE_BF16);
  unsigned short* WhiT = (unsigned short*)(ws + 2 * PLANE_BF16 + PLANE_F32);
  unsigned short* WloT = WhiT + 3 * 262144;

  prep_w_kernel<<<3072, 256, 0, stream>>>(W1, W2, W3, WhiT, WloT);

  ln_kernel<<<RTOT, 256, 0, stream>>>(Obs, g1, b1, Ahi, Alo);
  gemm_kernel<<<1024, 256, 0, stream>>>(Ahi, Alo, WhiT, WloT, F1, 0);

  ln_kernel<<<RTOT, 256, 0, stream>>>(F1, g2, b2, Ahi, Alo);
  gemm_kernel<<<1024, 256, 0, stream>>>(Ahi, Alo, WhiT + 262144, WloT + 262144, F1, 1);

  ln_kernel<<<RTOT, 256, 0, stream>>>(F1, g3, b3, Ahi, Alo);
  gemm_kernel<<<1024, 256, 0, stream>>>(Ahi, Alo, WhiT + 2 * 262144, WloT + 2 * 262144, F1, 2);

  softmax_kernel<<<1024, 256, 0, stream>>>(F1, msk, out);
}

// Round 3
// 344.084 us; speedup vs baseline: 1.7858x; 1.3533x over previous
//
#include <hip/hip_runtime.h>

// B=128, N=256, D=O=512. R = B*N = 32768 rows.
// LN1 -> GEMM1(tanh) -> LN2 -> GEMM2(tanh)+residual -> LN3 -> GEMM3 -> masked softmax over N.
// GEMMs: single-plane FP16 MFMA (error budget: logit err ~1e-4 << 1e-2 allowed).
// global_load_lds staging with XOR-swizzled layout (swizzle applied on the global
// address side, since DMA lane->LDS mapping is fixed at base + lane*16).
// Softmax: LDS-staged single-read per (b, o-chunk) block.

#define RTOT 32768
#define DDIM 512
#define BB   128
#define NN   256

#define TM   128
#define TN   128
#define BKC  64
#define LDSS 64   // packed rows (128 B) — required by global_load_lds lane layout

typedef _Float16 f16;
typedef __attribute__((ext_vector_type(8))) _Float16 f16x8;
typedef __attribute__((ext_vector_type(4))) float f32x4;

__device__ __forceinline__ float fast_tanh(float x) {
  float e = __expf(2.f * x);
  return 1.f - 2.f * __builtin_amdgcn_rcpf(e + 1.f);
}
__device__ __forceinline__ void async_copy16(const f16* g, f16* l) {
  __builtin_amdgcn_global_load_lds(
      (const __attribute__((address_space(1))) unsigned int*)g,
      (__attribute__((address_space(3))) unsigned int*)l, 16, 0, 0);
}

// ---- Transpose + f16-cast weights: W[d][o] fp32 -> WT[o][d] f16 ----
__global__ void prep_w_kernel(const float* __restrict__ W1, const float* __restrict__ W2,
                              const float* __restrict__ W3, f16* __restrict__ WT) {
  int idx = blockIdx.x * 256 + threadIdx.x;   // 3 * 512 * 512 total
  int s   = idx >> 18;
  int rem = idx & 0x3FFFF;
  int o   = rem >> 9;
  int d   = rem & 511;
  const float* W = (s == 0) ? W1 : (s == 1) ? W2 : W3;
  WT[idx] = (f16)W[d * 512 + o];
}

// ---- LayerNorm a 512-wide row, emit f16 plane ----
__global__ __launch_bounds__(256) void ln_kernel(const float* __restrict__ in,
                                                 const float* __restrict__ g,
                                                 const float* __restrict__ b,
                                                 f16* __restrict__ outA) {
  int row = blockIdx.x;
  int t = threadIdx.x;                 // 256 threads, 2 elems each
  const float* x = in + ((size_t)row << 9);
  float2 v = *(const float2*)(x + t * 2);
  float s  = v.x + v.y;
  float sq = v.x * v.x + v.y * v.y;
  #pragma unroll
  for (int off = 32; off > 0; off >>= 1) {
    s  += __shfl_down(s, off, 64);
    sq += __shfl_down(sq, off, 64);
  }
  __shared__ float ws_s[4], ws_q[4];
  int wave = t >> 6, lane = t & 63;
  if (lane == 0) { ws_s[wave] = s; ws_q[wave] = sq; }
  __syncthreads();
  float tot  = ws_s[0] + ws_s[1] + ws_s[2] + ws_s[3];
  float totq = ws_q[0] + ws_q[1] + ws_q[2] + ws_q[3];
  float mean = tot * (1.f / 512.f);
  float var  = totq * (1.f / 512.f) - mean * mean;
  float inv  = 1.f / sqrtf(var + 1e-5f);
  float2 gg = *(const float2*)(g + t * 2);
  float2 bb = *(const float2*)(b + t * 2);
  float o0 = (v.x - mean) * inv * gg.x + bb.x;
  float o1 = (v.y - mean) * inv * gg.y + bb.y;
  union { f16 h[2]; unsigned u; } pk;
  pk.h[0] = (f16)o0; pk.h[1] = (f16)o1;
  *(unsigned*)&outA[((size_t)row << 9) + t * 2] = pk.u;
}

// ---- FP16 GEMM: C[R x 512] = A[R x 512] @ W[512 x 512], W given as W^T ----
// stage 0: F = tanh(acc); stage 1: F = tanh(acc) + F; stage 2: F = acc
__global__ __launch_bounds__(256, 4) void gemm_kernel(
    const f16* __restrict__ A, const f16* __restrict__ BT,
    float* __restrict__ F, int stage) {
  __shared__ __align__(16) f16 sA[TM * LDSS];
  __shared__ __align__(16) f16 sB[TN * LDSS];

  int bx     = blockIdx.x;
  int rBase  = (bx >> 2) * TM;
  int nBase  = (bx & 3) * TN;

  int t     = threadIdx.x;
  int lane  = t & 63, wave = t >> 6;
  int wm    = wave & 1, wn = wave >> 1;
  int row16 = lane & 15, quad = lane >> 4;

  // DMA staging: waves 0,1 -> sA rows 0-63/64-127; waves 2,3 -> sB likewise.
  // XOR swizzle: LDS slot (r, s) holds global col-block s ^ (r&7); the DMA writes
  // lane l to slot (p*8 + (l>>3), l&7), so lane l fetches global block (l&7)^(l>>3).
  f16* ldsPlane = (wave < 2) ? sA : sB;
  const f16* gPlane = (wave < 2) ? A : BT;
  int tileBase = (wave < 2) ? rBase : nBase;
  int rowOff = (wave & 1) * 64;
  int lr  = lane >> 3;                        // row within 8-row group
  int lcs = ((lane & 7) ^ (lane >> 3)) * 8;   // swizzled col (ushorts)

  f32x4 acc[4][4] = {};

  for (int k0 = 0; k0 < 512; k0 += BKC) {
    #pragma unroll
    for (int p = 0; p < 8; ++p) {
      int r = rowOff + p * 8;
      const f16* g = gPlane + (((size_t)(tileBase + r + lr)) << 9) + k0 + lcs;
      async_copy16(g, ldsPlane + r * LDSS);   // wave-uniform LDS base
    }
    __syncthreads();

    #pragma unroll
    for (int kk = 0; kk < BKC; kk += 32) {
      f16x8 a[4], b[4];
      int kb = kk >> 3;                       // col-block offset (0 or 4)
      #pragma unroll
      for (int i = 0; i < 4; ++i) {
        int ar = wm * 64 + i * 16 + row16;
        int br = wn * 64 + i * 16 + row16;
        int ac = (quad + kb) ^ (ar & 7);
        int bc = (quad + kb) ^ (br & 7);
        a[i] = *(const f16x8*)&sA[ar * LDSS + ac * 8];
        b[i] = *(const f16x8*)&sB[br * LDSS + bc * 8];
      }
      #pragma unroll
      for (int mi = 0; mi < 4; ++mi)
        #pragma unroll
        for (int ni = 0; ni < 4; ++ni)
          acc[mi][ni] = __builtin_amdgcn_mfma_f32_16x16x32_f16(a[mi], b[ni], acc[mi][ni], 0, 0, 0);
    }
    __syncthreads();
  }

  #pragma unroll
  for (int mi = 0; mi < 4; ++mi) {
    #pragma unroll
    for (int ni = 0; ni < 4; ++ni) {
      int gc = nBase + wn * 64 + ni * 16 + row16;
      #pragma unroll
      for (int rg = 0; rg < 4; ++rg) {
        int gr = rBase + wm * 64 + mi * 16 + quad * 4 + rg;
        size_t idx = ((size_t)gr << 9) + gc;
        float v = acc[mi][ni][rg];
        if (stage == 0)      F[idx] = fast_tanh(v);
        else if (stage == 1) F[idx] = fast_tanh(v) + F[idx];
        else                 F[idx] = v;
      }
    }
  }
}

// ---- Masked softmax over N: one block per (b, 64-o chunk), z staged in LDS ----
__global__ __launch_bounds__(256, 2) void softmax_kernel(const float* __restrict__ o3,
                                                         const int* __restrict__ mask,
                                                         float* __restrict__ out) {
  __shared__ float sz[NN * 64];        // [n][o_l] 64 KB
  __shared__ float sredm[4 * 64];
  __shared__ float sreds[4 * 64];
  __shared__ int   smask[NN];

  int b  = blockIdx.x >> 3;
  int oc = blockIdx.x & 7;
  int t  = threadIdx.x;
  int o_l = t & 63;                    // o within chunk
  int n_h = t >> 6;                    // 0..3

  int mt = mask[b * NN + t];
  int any = __syncthreads_or(mt);
  smask[t] = (t == 0 && !any) ? 1 : mt;   // _grant_at_least_one_valid
  __syncthreads();

  const float* src = o3 + (((size_t)(b * NN)) << 9) + oc * 64;
  #pragma unroll 4
  for (int j = 0; j < 64; ++j) {
    int n = j * 4 + n_h;
    float v = src[((size_t)n << 9) + o_l];
    int m = smask[n];                  // wave-uniform broadcast
    sz[n * 64 + o_l] = m ? v : -3.4e38f;
  }
  __syncthreads();

  float mx = -3.4e38f;
  #pragma unroll 8
  for (int i = 0; i < 64; ++i)
    mx = fmaxf(mx, sz[(n_h * 64 + i) * 64 + o_l]);
  sredm[n_h * 64 + o_l] = mx;
  __syncthreads();
  float m4 = fmaxf(fmaxf(sredm[o_l], sredm[64 + o_l]),
                   fmaxf(sredm[128 + o_l], sredm[192 + o_l]));

  float sm = 0.f;
  #pragma unroll 8
  for (int i = 0; i < 64; ++i)
    sm += __expf(sz[(n_h * 64 + i) * 64 + o_l] - m4);
  sreds[n_h * 64 + o_l] = sm;
  __syncthreads();
  float tot = sreds[o_l] + sreds[64 + o_l] + sreds[128 + o_l] + sreds[192 + o_l];
  float inv = 1.f / tot;

  float* dst = out + (((size_t)(b * NN)) << 9) + oc * 64;
  #pragma unroll 4
  for (int j = 0; j < 64; ++j) {
    int n = j * 4 + n_h;
    float z = sz[n * 64 + o_l];
    dst[((size_t)n << 9) + o_l] = __expf(z - m4) * inv;
  }
}

extern "C" void kernel_launch(void* const* d_in, const int* in_sizes, int n_in,
                              void* d_out, int out_size, void* d_ws, size_t ws_size,
                              hipStream_t stream) {
  const float* Obs = (const float*)d_in[0];
  const int*   msk = (const int*)d_in[1];
  const float* g1  = (const float*)d_in[2];
  const float* b1  = (const float*)d_in[3];
  const float* W1  = (const float*)d_in[4];
  const float* g2  = (const float*)d_in[5];
  const float* b2  = (const float*)d_in[6];
  const float* W2  = (const float*)d_in[7];
  const float* g3  = (const float*)d_in[8];
  const float* b3  = (const float*)d_in[9];
  const float* W3  = (const float*)d_in[10];
  float* out = (float*)d_out;

  char* ws = (char*)d_ws;
  const size_t PLANE_F16 = (size_t)RTOT * DDIM * 2;   // 32 MB
  const size_t PLANE_F32 = (size_t)RTOT * DDIM * 4;   // 64 MB
  f16*   Ah = (f16*)ws;
  float* F1 = (float*)(ws + PLANE_F16);
  f16*   WT = (f16*)(ws + PLANE_F16 + PLANE_F32);

  prep_w_kernel<<<3072, 256, 0, stream>>>(W1, W2, W3, WT);

  ln_kernel<<<RTOT, 256, 0, stream>>>(Obs, g1, b1, Ah);
  gemm_kernel<<<1024, 256, 0, stream>>>(Ah, WT, F1, 0);

  ln_kernel<<<RTOT, 256, 0, stream>>>(F1, g2, b2, Ah);
  gemm_kernel<<<1024, 256, 0, stream>>>(Ah, WT + 262144, F1, 1);

  ln_kernel<<<RTOT, 256, 0, stream>>>(F1, g3, b3, Ah);
  gemm_kernel<<<1024, 256, 0, stream>>>(Ah, WT + 2 * 262144, F1, 2);

  softmax_kernel<<<1024, 256, 0, stream>>>(F1, msk, out);
}

// Round 4
// 303.844 us; speedup vs baseline: 2.0223x; 1.1324x over previous
//
#include <hip/hip_runtime.h>

// B=128, N=256, D=O=512. R = B*N = 32768 rows.
// Fused pipeline (5 kernels):
//   prep_w: W -> W^T f16
//   ln1:    LN(Obs) -> A1 f16
//   fused<0>: A1@W1, tanh -> h1 (f16, via LDS assemble), LN2 -> A2 f16
//   fused<1>: A2@W2, tanh + h1 (DMA'd back), LN3 -> A3 f16
//   fused<2>: A3@W3 -> logits fp32 (LDS-assembled full-line writes)
//   softmax: masked softmax over N
// Tile: TM=64 x TN=512 (full output width -> row-LN fusable), BK=64, 512 thr.
// All epilogue global writes are LDS-assembled (1024 B/instr) to kill L2
// write-allocate fetches (R3 counters: FETCH 99 MB = 32 ideal + 64 write-alloc).

#define RTOT 32768
#define NN   256

typedef _Float16 f16;
typedef __attribute__((ext_vector_type(4))) _Float16 f16x4;
typedef __attribute__((ext_vector_type(8))) _Float16 f16x8;
typedef __attribute__((ext_vector_type(4))) float f32x4;

#define EPS16 520   // f16 epilogue LDS row stride (1040 B: 16B-aligned, mild 4-way on b16 writes)
#define EPS32 516   // f32 epilogue LDS row stride (2064 B: 16B-aligned, 2-way = free)

__device__ __forceinline__ float fast_tanh(float x) {
  float e = __expf(2.f * x);
  return 1.f - 2.f * __builtin_amdgcn_rcpf(e + 1.f);
}
__device__ __forceinline__ void async_copy16(const void* g, void* l) {
  __builtin_amdgcn_global_load_lds(
      (const __attribute__((address_space(1))) unsigned int*)g,
      (__attribute__((address_space(3))) unsigned int*)l, 16, 0, 0);
}

// ---- Transpose + f16-cast weights: W[d][o] fp32 -> WT[o][d] f16 (3 stages) ----
__global__ void prep_w_kernel(const float* __restrict__ W1, const float* __restrict__ W2,
                              const float* __restrict__ W3, f16* __restrict__ WT) {
  int idx = blockIdx.x * 256 + threadIdx.x;
  int s   = idx >> 18;
  int rem = idx & 0x3FFFF;
  int o   = rem >> 9;
  int d   = rem & 511;
  const float* W = (s == 0) ? W1 : (s == 1) ? W2 : W3;
  WT[idx] = (f16)W[d * 512 + o];
}

// ---- LN1: wave-per-row, barrier-free ----
__global__ __launch_bounds__(256) void ln1_kernel(const float* __restrict__ in,
                                                  const float* __restrict__ g,
                                                  const float* __restrict__ b,
                                                  f16* __restrict__ outA) {
  int wv = threadIdx.x >> 6, lane = threadIdx.x & 63;
  size_t row = (size_t)blockIdx.x * 4 + wv;
  const float* x = in + (row << 9);
  float4 v0 = *(const float4*)(x + lane * 4);
  float4 v1 = *(const float4*)(x + 256 + lane * 4);
  float s = v0.x + v0.y + v0.z + v0.w + v1.x + v1.y + v1.z + v1.w;
  float q = v0.x*v0.x + v0.y*v0.y + v0.z*v0.z + v0.w*v0.w
          + v1.x*v1.x + v1.y*v1.y + v1.z*v1.z + v1.w*v1.w;
  #pragma unroll
  for (int off = 1; off < 64; off <<= 1) {
    s += __shfl_xor(s, off, 64);
    q += __shfl_xor(q, off, 64);
  }
  float mean = s * (1.f / 512.f);
  float var  = q * (1.f / 512.f) - mean * mean;
  float inv  = 1.f / sqrtf(var + 1e-5f);
  float4 g0 = *(const float4*)(g + lane * 4);
  float4 b0 = *(const float4*)(b + lane * 4);
  float4 g1 = *(const float4*)(g + 256 + lane * 4);
  float4 b1 = *(const float4*)(b + 256 + lane * 4);
  f16x4 o0, o1;
  o0[0] = (f16)((v0.x - mean) * inv * g0.x + b0.x);
  o0[1] = (f16)((v0.y - mean) * inv * g0.y + b0.y);
  o0[2] = (f16)((v0.z - mean) * inv * g0.z + b0.z);
  o0[3] = (f16)((v0.w - mean) * inv * g0.w + b0.w);
  o1[0] = (f16)((v1.x - mean) * inv * g1.x + b1.x);
  o1[1] = (f16)((v1.y - mean) * inv * g1.y + b1.y);
  o1[2] = (f16)((v1.z - mean) * inv * g1.z + b1.z);
  o1[3] = (f16)((v1.w - mean) * inv * g1.w + b1.w);
  *(f16x4*)&outA[(row << 9) + lane * 4] = o0;
  *(f16x4*)&outA[(row << 9) + 256 + lane * 4] = o1;
}

// ---- Fused GEMM (+tanh[, +residual], +LN) ----
// STAGE 0: outH=A2=LN2(tanh(A@W)), H1 <- tanh(A@W)
// STAGE 1: outH=A3=LN3(tanh(A@W) + H1)
// STAGE 2: outF=A@W (fp32 logits)
template <int STAGE>
__global__ __launch_bounds__(512, 4) void fused_kernel(
    const f16* __restrict__ A, const f16* __restrict__ BT,
    const float* __restrict__ g, const float* __restrict__ b,
    f16* __restrict__ H1, f16* __restrict__ outH, float* __restrict__ outF) {
  __shared__ __align__(16) char smem[73728];     // sA(8K)+sB(64K); epilogue overlays
  __shared__ __align__(16) float2 sPart[512];    // [wave][row]
  __shared__ __align__(16) float2 sStat[64];     // (mean, inv) per row
  f16* sA = (f16*)smem;
  f16* sB = (f16*)(smem + 8192);

  int t = threadIdx.x, lane = t & 63, wv = t >> 6;
  int row16 = lane & 15, quad = lane >> 4;
  int rBase = blockIdx.x * 64;
  int lr  = lane >> 3;
  int lcs = ((lane & 7) ^ (lane >> 3)) * 8;   // swizzled col-block (global side)

  f32x4 acc[4][4] = {};

  for (int k0 = 0; k0 < 512; k0 += 64) {
    {
      const f16* ga = A + (((size_t)(rBase + wv * 8 + lr)) << 9) + k0 + lcs;
      async_copy16(ga, sA + (wv * 8) * 64);
    }
    #pragma unroll
    for (int p = 0; p < 8; ++p) {
      int r = wv * 64 + p * 8;
      const f16* gb = BT + (((size_t)(r + lr)) << 9) + k0 + lcs;
      async_copy16(gb, sB + r * 64);
    }
    __syncthreads();
    #pragma unroll
    for (int kk = 0; kk < 64; kk += 32) {
      int kb = kk >> 3;
      f16x8 af[4], bf[4];
      #pragma unroll
      for (int i = 0; i < 4; ++i) {
        int ar = i * 16 + row16;
        int br = wv * 64 + i * 16 + row16;
        af[i] = *(const f16x8*)&sA[ar * 64 + (((quad + kb) ^ (ar & 7)) << 3)];
        bf[i] = *(const f16x8*)&sB[br * 64 + (((quad + kb) ^ (br & 7)) << 3)];
      }
      #pragma unroll
      for (int mi = 0; mi < 4; ++mi)
        #pragma unroll
        for (int ni = 0; ni < 4; ++ni)
          acc[mi][ni] = __builtin_amdgcn_mfma_f32_16x16x32_f16(af[mi], bf[ni], acc[mi][ni], 0, 0, 0);
    }
    __syncthreads();
  }

  if constexpr (STAGE == 2) {
    float* sE = (float*)smem;   // stride EPS32
    #pragma unroll
    for (int half = 0; half < 2; ++half) {
      #pragma unroll
      for (int mi = 0; mi < 2; ++mi) {
        int rt = half * 2 + mi;
        #pragma unroll
        for (int ni = 0; ni < 4; ++ni) {
          int col = wv * 64 + ni * 16 + row16;
          #pragma unroll
          for (int rg = 0; rg < 4; ++rg)
            sE[(mi * 16 + quad * 4 + rg) * EPS32 + col] = acc[rt][ni][rg];
        }
      }
      __syncthreads();
      #pragma unroll
      for (int i = 0; i < 8; ++i) {
        int gi = t + i * 512;
        int row = gi >> 7, cg = (gi & 127) * 4;
        f32x4 v = *(const f32x4*)&sE[row * EPS32 + cg];
        *(f32x4*)&outF[(((size_t)(rBase + half * 32 + row)) << 9) + cg] = v;
      }
      __syncthreads();
    }
    return;
  } else {
    float gv[4], bv[4];
    #pragma unroll
    for (int ni = 0; ni < 4; ++ni) {
      int c = wv * 64 + ni * 16 + row16;
      gv[ni] = g[c]; bv[ni] = b[c];
    }

    f16* sH = (f16*)smem;   // packed [64][512] (stage 1 residual DMA)
    if constexpr (STAGE == 1) {
      #pragma unroll
      for (int p = 0; p < 8; ++p) {
        const f16* gh = H1 + (((size_t)(rBase + wv * 8 + p)) << 9) + lane * 8;
        async_copy16(gh, sH + (wv * 8 + p) * 512);
      }
    }

    #pragma unroll
    for (int mi = 0; mi < 4; ++mi)
      #pragma unroll
      for (int ni = 0; ni < 4; ++ni)
        #pragma unroll
        for (int rg = 0; rg < 4; ++rg)
          acc[mi][ni][rg] = fast_tanh(acc[mi][ni][rg]);

    if constexpr (STAGE == 1) {
      __syncthreads();    // DMA complete
      #pragma unroll
      for (int mi = 0; mi < 4; ++mi)
        #pragma unroll
        for (int ni = 0; ni < 4; ++ni) {
          int col = wv * 64 + ni * 16 + row16;
          #pragma unroll
          for (int rg = 0; rg < 4; ++rg)
            acc[mi][ni][rg] += (float)sH[(mi * 16 + quad * 4 + rg) * 512 + col];
        }
    }

    f16* sE = (f16*)smem;   // stride EPS16
    if constexpr (STAGE == 0) {
      // stash h1 (pre-LN) into LDS for assembled write-out
      #pragma unroll
      for (int mi = 0; mi < 4; ++mi)
        #pragma unroll
        for (int ni = 0; ni < 4; ++ni) {
          int col = wv * 64 + ni * 16 + row16;
          #pragma unroll
          for (int rg = 0; rg < 4; ++rg)
            sE[(mi * 16 + quad * 4 + rg) * EPS16 + col] = (f16)acc[mi][ni][rg];
        }
    }

    // per-row stats: lane partial over ni, butterfly over row16 (16-lane groups)
    #pragma unroll
    for (int mi = 0; mi < 4; ++mi)
      #pragma unroll
      for (int rg = 0; rg < 4; ++rg) {
        float s = 0.f, q = 0.f;
        #pragma unroll
        for (int ni = 0; ni < 4; ++ni) {
          float v = acc[mi][ni][rg];
          s += v; q += v * v;
        }
        #pragma unroll
        for (int off = 1; off < 16; off <<= 1) {
          s += __shfl_xor(s, off, 16);
          q += __shfl_xor(q, off, 16);
        }
        if (row16 == 0)
          sPart[wv * 64 + mi * 16 + quad * 4 + rg] = make_float2(s, q);
      }
    __syncthreads();   // sPart ready; (STAGE 0) sE h1 writes done; (STAGE 1) sH reads done

    if (t < 64) {
      float s = 0.f, q = 0.f;
      #pragma unroll
      for (int w = 0; w < 8; ++w) {
        float2 p = sPart[w * 64 + t];
        s += p.x; q += p.y;
      }
      float mean = s * (1.f / 512.f);
      float var  = q * (1.f / 512.f) - mean * mean;
      sStat[t] = make_float2(mean, 1.f / sqrtf(var + 1e-5f));
    }
    if constexpr (STAGE == 0) {
      // write out h1 (full-line assembled)
      #pragma unroll
      for (int i = 0; i < 8; ++i) {
        int gi = t + i * 512;
        int row = gi >> 6, cg = (gi & 63) * 8;
        f16x8 v = *(const f16x8*)&sE[row * EPS16 + cg];
        *(f16x8*)&H1[(((size_t)(rBase + row)) << 9) + cg] = v;
      }
    }
    __syncthreads();   // sStat ready; sE free for a-plane

    #pragma unroll
    for (int mi = 0; mi < 4; ++mi)
      #pragma unroll
      for (int rg = 0; rg < 4; ++rg) {
        int row = mi * 16 + quad * 4 + rg;
        float2 st = sStat[row];
        #pragma unroll
        for (int ni = 0; ni < 4; ++ni) {
          int col = wv * 64 + ni * 16 + row16;
          sE[row * EPS16 + col] = (f16)((acc[mi][ni][rg] - st.x) * st.y * gv[ni] + bv[ni]);
        }
      }
    __syncthreads();

    #pragma unroll
    for (int i = 0; i < 8; ++i) {
      int gi = t + i * 512;
      int row = gi >> 6, cg = (gi & 63) * 8;
      f16x8 v = *(const f16x8*)&sE[row * EPS16 + cg];
      *(f16x8*)&outH[(((size_t)(rBase + row)) << 9) + cg] = v;
    }
  }
}

// ---- Masked softmax over N: one block per (b, 64-o chunk), z staged in LDS ----
__global__ __launch_bounds__(256, 2) void softmax_kernel(const float* __restrict__ o3,
                                                         const int* __restrict__ mask,
                                                         float* __restrict__ out) {
  __shared__ float sz[NN * 64];
  __shared__ float sredm[4 * 64];
  __shared__ float sreds[4 * 64];
  __shared__ int   smask[NN];

  int b  = blockIdx.x >> 3;
  int oc = blockIdx.x & 7;
  int t  = threadIdx.x;
  int o_l = t & 63;
  int n_h = t >> 6;

  int mt = mask[b * NN + t];
  int any = __syncthreads_or(mt);
  smask[t] = (t == 0 && !any) ? 1 : mt;
  __syncthreads();

  const float* src = o3 + (((size_t)(b * NN)) << 9) + oc * 64;
  #pragma unroll 4
  for (int j = 0; j < 64; ++j) {
    int n = j * 4 + n_h;
    float v = src[((size_t)n << 9) + o_l];
    sz[n * 64 + o_l] = smask[n] ? v : -3.4e38f;
  }
  __syncthreads();

  float mx = -3.4e38f;
  #pragma unroll 8
  for (int i = 0; i < 64; ++i)
    mx = fmaxf(mx, sz[(n_h * 64 + i) * 64 + o_l]);
  sredm[n_h * 64 + o_l] = mx;
  __syncthreads();
  float m4 = fmaxf(fmaxf(sredm[o_l], sredm[64 + o_l]),
                   fmaxf(sredm[128 + o_l], sredm[192 + o_l]));

  float sm = 0.f;
  #pragma unroll 8
  for (int i = 0; i < 64; ++i)
    sm += __expf(sz[(n_h * 64 + i) * 64 + o_l] - m4);
  sreds[n_h * 64 + o_l] = sm;
  __syncthreads();
  float tot = sreds[o_l] + sreds[64 + o_l] + sreds[128 + o_l] + sreds[192 + o_l];
  float inv = 1.f / tot;

  float* dst = out + (((size_t)(b * NN)) << 9) + oc * 64;
  #pragma unroll 4
  for (int j = 0; j < 64; ++j) {
    int n = j * 4 + n_h;
    dst[((size_t)n << 9) + o_l] = __expf(sz[n * 64 + o_l] - m4) * inv;
  }
}

extern "C" void kernel_launch(void* const* d_in, const int* in_sizes, int n_in,
                              void* d_out, int out_size, void* d_ws, size_t ws_size,
                              hipStream_t stream) {
  const float* Obs = (const float*)d_in[0];
  const int*   msk = (const int*)d_in[1];
  const float* g1  = (const float*)d_in[2];
  const float* b1  = (const float*)d_in[3];
  const float* W1  = (const float*)d_in[4];
  const float* g2  = (const float*)d_in[5];
  const float* b2  = (const float*)d_in[6];
  const float* W2  = (const float*)d_in[7];
  const float* g3  = (const float*)d_in[8];
  const float* b3  = (const float*)d_in[9];
  const float* W3  = (const float*)d_in[10];
  float* out = (float*)d_out;

  char* ws = (char*)d_ws;
  const size_t MB = 1u << 20;
  f16*   Ah0 = (f16*)ws;                   // [0, 32M)
  f16*   Ah1 = (f16*)(ws + 32 * MB);       // [32M, 64M)
  f16*   H1h = (f16*)(ws + 64 * MB);       // [64M, 96M) — dead after stage 1
  float* Lg  = (float*)(ws + 64 * MB);     // [64M, 128M) logits, overlays H1h
  f16*   WT  = (f16*)(ws + 128 * MB);      // 1.5 MB

  prep_w_kernel<<<3072, 256, 0, stream>>>(W1, W2, W3, WT);
  ln1_kernel<<<8192, 256, 0, stream>>>(Obs, g1, b1, Ah0);
  fused_kernel<0><<<512, 512, 0, stream>>>(Ah0, WT,          g2, b2, H1h, Ah1, nullptr);
  fused_kernel<1><<<512, 512, 0, stream>>>(Ah1, WT + 262144, g3, b3, H1h, Ah0, nullptr);
  fused_kernel<2><<<512, 512, 0, stream>>>(Ah0, WT + 524288, nullptr, nullptr, nullptr, nullptr, Lg);
  softmax_kernel<<<1024, 256, 0, stream>>>(Lg, msk, out);
}